// Round 9
// baseline (344.598 us; speedup 1.0000x reference)
//
#include <hip/hip_runtime.h>
#include <math.h>

#define NUM_CODES 128
#define CODE_DIM  64
#define B_ 64
#define D_ 64
#define T_ 8192
#define N_TOK (B_ * T_)   // 524288

typedef __attribute__((ext_vector_type(8))) short bf16x8;
typedef __attribute__((ext_vector_type(4))) float f32x4;

union BU { uint4 q; bf16x8 v; unsigned short h[8]; unsigned int u[4]; };

// bf16 round-to-nearest-even from fp32, and exact widening back
__device__ __forceinline__ unsigned short bf16_rne(float x) {
    unsigned int u = __float_as_uint(x);
    unsigned int r = u + 0x7fffu + ((u >> 16) & 1u);
    return (unsigned short)(r >> 16);
}
__device__ __forceinline__ float bf16_f(unsigned short h) {
    return __uint_as_float(((unsigned int)h) << 16);
}

// ws layout (floats): [0..127] c2h | [128..255] counts(uint) | [256..] bfrags
// bfrags: 48 frags (p:3 x ntile:8 x kstep:2) x 64 lanes x 16B, frag-linear in
// the exact order lanes read them -> conflict-free ds_read_b128.
// frag_id = ((p*8 + nt)*2 + ks); element j: plane p of
// C[code = nt*16 + (lane&15)][k = ks*32 + (lane>>4)*8 + j]
// ---------------------------------------------------------------------------
__global__ __launch_bounds__(256) void kmeans_prep(
    const float* __restrict__ centroids, float* __restrict__ ws_f)
{
    const int tid = threadIdx.x;
    float*        c2h    = ws_f;
    unsigned int* counts = (unsigned int*)(ws_f + 128);
    unsigned int* frag   = (unsigned int*)(ws_f + 256);

    if (tid < NUM_CODES) {
        // EXACT round-4 prep arithmetic for c2h
        const float* cp = centroids + tid * CODE_DIM;
        float s0 = 0.f, s1 = 0.f, s2 = 0.f, s3 = 0.f;
        #pragma unroll
        for (int d = 0; d < CODE_DIM; d += 4) {
            s0 = fmaf(cp[d + 0], cp[d + 0], s0);
            s1 = fmaf(cp[d + 1], cp[d + 1], s1);
            s2 = fmaf(cp[d + 2], cp[d + 2], s2);
            s3 = fmaf(cp[d + 3], cp[d + 3], s3);
        }
        c2h[tid] = 0.5f * ((s0 + s1) + (s2 + s3));
        counts[tid] = 0u;
    }

    // 48 frags x 64 lanes = 3072 entries; 12 per thread
    for (int e = tid; e < 3072; e += 256) {
        int fid  = e >> 6;
        int lane = e & 63;
        int ks   = fid & 1;
        int nt   = (fid >> 1) & 7;
        int p    = fid >> 4;              // 0,1,2
        int code = nt * 16 + (lane & 15);
        int k0   = ks * 32 + (lane >> 4) * 8;
        const float* cp = centroids + code * CODE_DIM + k0;
        unsigned short hb[8];
        #pragma unroll
        for (int j = 0; j < 8; ++j) {
            float x = cp[j];
            unsigned short b1 = bf16_rne(x);
            float r1 = x - bf16_f(b1);
            unsigned short b2 = bf16_rne(r1);
            float r2 = r1 - bf16_f(b2);
            unsigned short b3 = bf16_rne(r2);
            hb[j] = (p == 0) ? b1 : (p == 1) ? b2 : b3;
        }
        unsigned int* dst = frag + fid * 256 + lane * 4;
        #pragma unroll
        for (int w2 = 0; w2 < 4; ++w2)
            dst[w2] = (unsigned int)hb[2 * w2] | ((unsigned int)hb[2 * w2 + 1] << 16);
    }
}

// ---------------------------------------------------------------------------
// assign: 64 tokens/block, 4 waves; wave w = one 16-token m-tile.
// MFMA 16x16x32 bf16, bf16x3 split (6 products: 11,12,21,22,13,31) -> ~fp32
// accuracy. C/D layout (m91-verified): col=lane&15(code), row=(lane>>4)*4+reg.
// Top-2 candidates per token (in-reg scan + 16-lane xor merge), then EXACT
// fp32 judge in the bitwise round-4 chain order (absmax-0 proven) with
// ascending-k strict tie-break.
// ---------------------------------------------------------------------------
__global__ __launch_bounds__(256, 3) void kmeans_assign(
    const float* __restrict__ z_e, const float* __restrict__ centroids,
    const float* __restrict__ ws_f, unsigned int* __restrict__ counts,
    float* __restrict__ out_idx)
{
    __shared__ unsigned int bfr[12288];     // 48 KB: 48 frags x 256 u32
    __shared__ float        c2l[NUM_CODES];
    __shared__ unsigned int cand[64];
    __shared__ unsigned int hist[NUM_CODES];

    const int tid  = threadIdx.x;
    const int lane = tid & 63;
    const int w    = tid >> 6;

    // stage B-frags (3072 uint4 / 256 thr = 12 each), c2h, zero hist
    {
        const uint4* src = (const uint4*)(ws_f + 256);
        uint4*       dst = (uint4*)bfr;
        #pragma unroll
        for (int r = 0; r < 12; ++r) dst[r * 256 + tid] = src[r * 256 + tid];
        if (tid < NUM_CODES) { c2l[tid] = ws_f[tid]; hist[tid] = 0u; }
    }

    // A-frags: token = base + (lane&15), k = ks*32 + (lane>>4)*8 + j
    const int base = blockIdx.x * 64;            // block token base
    const int b    = base >> 13;
    const int t0   = base & (T_ - 1);
    const float* zw = z_e + (size_t)b * (size_t)(D_ * T_) + t0 + w * 16 + (lane & 15);

    BU A1[2], A2[2], A3[2];
    #pragma unroll
    for (int ks = 0; ks < 2; ++ks) {
        const int k0 = ks * 32 + (lane >> 4) * 8;
        #pragma unroll
        for (int j = 0; j < 8; ++j) {
            float x = zw[(size_t)(k0 + j) * T_];
            unsigned short b1 = bf16_rne(x);
            float r1 = x - bf16_f(b1);
            unsigned short b2 = bf16_rne(r1);
            float r2 = r1 - bf16_f(b2);
            unsigned short b3 = bf16_rne(r2);
            A1[ks].h[j] = b1; A2[ks].h[j] = b2; A3[ks].h[j] = b3;
        }
    }

    __syncthreads();

    f32x4 acc[8];
    #pragma unroll
    for (int nt = 0; nt < 8; ++nt) acc[nt] = (f32x4){0.f, 0.f, 0.f, 0.f};

    const int lbase = lane * 4;
    #pragma unroll
    for (int nt = 0; nt < 8; ++nt) {
        #pragma unroll
        for (int ks = 0; ks < 2; ++ks) {
            BU B1, B2, B3;
            B1.q = *(const uint4*)(bfr + ((0 * 8 + nt) * 2 + ks) * 256 + lbase);
            B2.q = *(const uint4*)(bfr + ((1 * 8 + nt) * 2 + ks) * 256 + lbase);
            B3.q = *(const uint4*)(bfr + ((2 * 8 + nt) * 2 + ks) * 256 + lbase);
            acc[nt] = __builtin_amdgcn_mfma_f32_16x16x32_bf16(A1[ks].v, B1.v, acc[nt], 0, 0, 0);
            acc[nt] = __builtin_amdgcn_mfma_f32_16x16x32_bf16(A1[ks].v, B2.v, acc[nt], 0, 0, 0);
            acc[nt] = __builtin_amdgcn_mfma_f32_16x16x32_bf16(A2[ks].v, B1.v, acc[nt], 0, 0, 0);
            acc[nt] = __builtin_amdgcn_mfma_f32_16x16x32_bf16(A2[ks].v, B2.v, acc[nt], 0, 0, 0);
            acc[nt] = __builtin_amdgcn_mfma_f32_16x16x32_bf16(A1[ks].v, B3.v, acc[nt], 0, 0, 0);
            acc[nt] = __builtin_amdgcn_mfma_f32_16x16x32_bf16(A3[ks].v, B1.v, acc[nt], 0, 0, 0);
        }
    }

    // per-row top-2 scan over 8 n-tiles (codes ascending)
    float s1[4], s2[4]; int c1[4], c2v[4];
    #pragma unroll
    for (int j = 0; j < 4; ++j) { s1[j] = s2[j] = -3.4e38f; c1[j] = c2v[j] = 0; }
    #pragma unroll
    for (int nt = 0; nt < 8; ++nt) {
        const int  code = nt * 16 + (lane & 15);
        const float csub = c2l[code];
        #pragma unroll
        for (int j = 0; j < 4; ++j) {
            float s = acc[nt][j] - csub;
            if (s > s1[j])      { s2[j] = s1[j]; c2v[j] = c1[j]; s1[j] = s; c1[j] = code; }
            else if (s > s2[j]) { s2[j] = s;     c2v[j] = code; }
        }
    }
    // merge across the 16 lanes holding this row (xor 1,2,4,8)
    #pragma unroll
    for (int m = 1; m <= 8; m <<= 1) {
        #pragma unroll
        for (int j = 0; j < 4; ++j) {
            float os1 = __shfl_xor(s1[j], m); int oc1 = __shfl_xor(c1[j], m);
            float os2 = __shfl_xor(s2[j], m); int oc2 = __shfl_xor(c2v[j], m);
            bool a  = (os1 > s1[j]) || (os1 == s1[j] && oc1 < c1[j]);
            float n1 = a ? os1 : s1[j]; int nc1 = a ? oc1 : c1[j];
            float l1 = a ? s1[j] : os1; int lc1 = a ? c1[j] : oc1;
            bool bs = (os2 > s2[j]) || (os2 == s2[j] && oc2 < c2v[j]);
            float w2 = bs ? os2 : s2[j]; int wc2 = bs ? oc2 : c2v[j];
            bool c3 = (l1 > w2) || (l1 == w2 && lc1 < wc2);
            s1[j] = n1; c1[j] = nc1;
            s2[j] = c3 ? l1 : w2; c2v[j] = c3 ? lc1 : wc2;
        }
    }
    if ((lane & 15) == 0) {
        const int g = lane >> 4;
        #pragma unroll
        for (int j = 0; j < 4; ++j) {
            int ka = c1[j], kb = c2v[j];
            int kmin = min(ka, kb), kmax = max(ka, kb);
            cand[w * 16 + g * 4 + j] = ((unsigned int)kmin << 8) | (unsigned int)kmax;
        }
    }
    __syncthreads();

    // EXACT judge: thread tid<64 owns token base+tid; round-4 bitwise chains
    if (tid < 64) {
        unsigned int cp_ = cand[tid];
        int k1 = (int)(cp_ >> 8), k2 = (int)(cp_ & 255u);   // k1 < k2
        const float* zp = z_e + (size_t)b * (size_t)(D_ * T_) + t0 + tid;
        float z[64];
        #pragma unroll
        for (int d = 0; d < 64; ++d) z[d] = zp[(size_t)d * T_];

        float m1, m2;
        {
            const float* cp = centroids + k1 * CODE_DIM;
            float a0 = -c2l[k1], a1 = 0.f;
            #pragma unroll
            for (int d = 0; d < 64; d += 2) {
                a0 = fmaf(cp[d],     z[d],     a0);
                a1 = fmaf(cp[d + 1], z[d + 1], a1);
            }
            m1 = a0 + a1;
        }
        {
            const float* cp = centroids + k2 * CODE_DIM;
            float a0 = -c2l[k2], a1 = 0.f;
            #pragma unroll
            for (int d = 0; d < 64; d += 2) {
                a0 = fmaf(cp[d],     z[d],     a0);
                a1 = fmaf(cp[d + 1], z[d + 1], a1);
            }
            m2 = a0 + a1;
        }
        int bi = (m2 > m1) ? k2 : k1;      // strict: tie keeps lower k
        out_idx[base + tid] = (float)bi;
        atomicAdd(&hist[bi], 1u);
    }
    __syncthreads();
    if (tid < NUM_CODES) {
        unsigned int h = hist[tid];
        if (h) atomicAdd(&counts[tid], h);
    }
}

// ---------------------------------------------------------------------------
// finalize: entropy -> perplexity, usage
// ---------------------------------------------------------------------------
__global__ __launch_bounds__(128) void kmeans_finalize(
    const unsigned int* __restrict__ counts, float* __restrict__ out)
{
    const int k = threadIdx.x;
    unsigned int c = counts[k];
    float p = fmaxf((float)c * (1.0f / (float)N_TOK), 1e-12f);
    float h = -p * logf(p);
    float u = (c > 0u) ? 1.0f : 0.0f;

    __shared__ float sh[NUM_CODES];
    __shared__ float su[NUM_CODES];
    sh[k] = h; su[k] = u;
    __syncthreads();
    for (int s = 64; s > 0; s >>= 1) {
        if (k < s) { sh[k] += sh[k + s]; su[k] += su[k + s]; }
        __syncthreads();
    }
    if (k == 0) {
        out[N_TOK + 0] = expf(sh[0]);
        out[N_TOK + 1] = su[0] * (1.0f / 128.f);
    }
}

// ---------------------------------------------------------------------------
extern "C" void kernel_launch(void* const* d_in, const int* in_sizes, int n_in,
                              void* d_out, int out_size, void* d_ws, size_t ws_size,
                              hipStream_t stream)
{
    const float* z_e       = (const float*)d_in[0];
    const float* centroids = (const float*)d_in[1];
    float* out  = (float*)d_out;
    float* ws_f = (float*)d_ws;
    unsigned int* counts = (unsigned int*)(ws_f + 128);

    kmeans_prep<<<1, 256, 0, stream>>>(centroids, ws_f);
    kmeans_assign<<<N_TOK / 64, 256, 0, stream>>>(z_e, centroids, ws_f, counts, out);
    kmeans_finalize<<<1, 128, 0, stream>>>(counts, out);
}

// Round 10
// 285.575 us; speedup vs baseline: 1.2067x; 1.2067x over previous
//
#include <hip/hip_runtime.h>
#include <math.h>

#define NUM_CODES 128
#define CODE_DIM  64
#define B_ 64
#define D_ 64
#define T_ 8192
#define N_TOK (B_ * T_)   // 524288

typedef __attribute__((ext_vector_type(8))) short bf16x8;
typedef __attribute__((ext_vector_type(4))) float f32x4;

union BU { uint4 q; bf16x8 v; unsigned short h[8]; unsigned int u[4]; };

// bf16 round-to-nearest-even from fp32, and exact widening back
__device__ __forceinline__ unsigned short bf16_rne(float x) {
    unsigned int u = __float_as_uint(x);
    unsigned int r = u + 0x7fffu + ((u >> 16) & 1u);
    return (unsigned short)(r >> 16);
}
__device__ __forceinline__ float bf16_f(unsigned short h) {
    return __uint_as_float(((unsigned int)h) << 16);
}

// ws layout (floats): [0..127] c2h | [128..255] counts(uint) | [256..] bfrags
// bfrags: 48 frags (p:3 x ntile:8 x kstep:2) x 64 lanes x 16B, frag-linear in
// the exact order lanes read them -> conflict-free ds_read_b128.
// frag_id = ((p*8 + nt)*2 + ks); element j: plane p of
// C[code = nt*16 + (lane&15)][k = ks*32 + (lane>>4)*8 + j]
// (unchanged from round 9 — proven absmax 0)
// ---------------------------------------------------------------------------
__global__ __launch_bounds__(256) void kmeans_prep(
    const float* __restrict__ centroids, float* __restrict__ ws_f)
{
    const int tid = threadIdx.x;
    float*        c2h    = ws_f;
    unsigned int* counts = (unsigned int*)(ws_f + 128);
    unsigned int* frag   = (unsigned int*)(ws_f + 256);

    if (tid < NUM_CODES) {
        // EXACT round-4 prep arithmetic for c2h
        const float* cp = centroids + tid * CODE_DIM;
        float s0 = 0.f, s1 = 0.f, s2 = 0.f, s3 = 0.f;
        #pragma unroll
        for (int d = 0; d < CODE_DIM; d += 4) {
            s0 = fmaf(cp[d + 0], cp[d + 0], s0);
            s1 = fmaf(cp[d + 1], cp[d + 1], s1);
            s2 = fmaf(cp[d + 2], cp[d + 2], s2);
            s3 = fmaf(cp[d + 3], cp[d + 3], s3);
        }
        c2h[tid] = 0.5f * ((s0 + s1) + (s2 + s3));
        counts[tid] = 0u;
    }

    // 48 frags x 64 lanes = 3072 entries; 12 per thread
    for (int e = tid; e < 3072; e += 256) {
        int fid  = e >> 6;
        int lane = e & 63;
        int ks   = fid & 1;
        int nt   = (fid >> 1) & 7;
        int p    = fid >> 4;              // 0,1,2
        int code = nt * 16 + (lane & 15);
        int k0   = ks * 32 + (lane >> 4) * 8;
        const float* cp = centroids + code * CODE_DIM + k0;
        unsigned short hb[8];
        #pragma unroll
        for (int j = 0; j < 8; ++j) {
            float x = cp[j];
            unsigned short b1 = bf16_rne(x);
            float r1 = x - bf16_f(b1);
            unsigned short b2 = bf16_rne(r1);
            float r2 = r1 - bf16_f(b2);
            unsigned short b3 = bf16_rne(r2);
            hb[j] = (p == 0) ? b1 : (p == 1) ? b2 : b3;
        }
        unsigned int* dst = frag + fid * 256 + lane * 4;
        #pragma unroll
        for (int w2 = 0; w2 < 4; ++w2)
            dst[w2] = (unsigned int)hb[2 * w2] | ((unsigned int)hb[2 * w2 + 1] << 16);
    }
}

// ---------------------------------------------------------------------------
// assign: 256 tokens/block, 4 waves; wave w runs 4 sequential 16-token
// m-tile passes against the SAME LDS B-frags (staging/barriers amortized 4x
// vs round 9). MFMA 16x16x32 bf16, bf16x3 split (products 11,12,21,22,13,31).
// A-split by truncation (exact Dekker residuals, ~2^-23 rel method error).
// Top-2 per token (round-9 scan + 16-lane xor merge, verbatim), then EXACT
// fp32 judge distributed 1 token/thread (bitwise round-4 chains, proven
// absmax-0) with ascending-k strict tie-break.
// ---------------------------------------------------------------------------
__global__ __launch_bounds__(256, 3) void kmeans_assign(
    const float* __restrict__ z_e, const float* __restrict__ centroids,
    const float* __restrict__ ws_f, unsigned int* __restrict__ counts,
    float* __restrict__ out_idx)
{
    __shared__ unsigned int bfr[12288];     // 48 KB: 48 frags x 256 u32
    __shared__ float        c2l[NUM_CODES];
    __shared__ unsigned int cand[256];
    __shared__ unsigned int hist[NUM_CODES];

    const int tid  = threadIdx.x;
    const int lane = tid & 63;
    const int w    = tid >> 6;

    // stage B-frags (3072 uint4 / 256 thr = 12 each), c2h, zero hist
    {
        const uint4* src = (const uint4*)(ws_f + 256);
        uint4*       dst = (uint4*)bfr;
        #pragma unroll
        for (int r = 0; r < 12; ++r) dst[r * 256 + tid] = src[r * 256 + tid];
        if (tid < NUM_CODES) { c2l[tid] = ws_f[tid]; hist[tid] = 0u; }
    }

    const int base = blockIdx.x * 256;           // block token base
    const int b    = base >> 13;
    const int t0   = base & (T_ - 1);

    __syncthreads();

    const int lbase = lane * 4;

    #pragma unroll
    for (int mt = 0; mt < 4; ++mt) {
        // A-frags: token = base + w*64 + mt*16 + (lane&15),
        //          k = ks*32 + (lane>>4)*8 + j   (round-9 mapping, proven)
        const float* zw = z_e + (size_t)b * (size_t)(D_ * T_) + t0
                        + w * 64 + mt * 16 + (lane & 15);
        BU A1[2], A2[2], A3[2];
        #pragma unroll
        for (int ks = 0; ks < 2; ++ks) {
            const int k0 = ks * 32 + (lane >> 4) * 8;
            #pragma unroll
            for (int j = 0; j < 8; ++j) {
                float x = zw[(size_t)(k0 + j) * T_];
                unsigned int u  = __float_as_uint(x);
                unsigned int b1 = u & 0xFFFF0000u;          // trunc split:
                float r1 = x - __uint_as_float(b1);         // residuals exact
                unsigned int u1 = __float_as_uint(r1);
                unsigned int b2 = u1 & 0xFFFF0000u;
                float r2 = r1 - __uint_as_float(b2);
                unsigned int b3 = __float_as_uint(r2);
                A1[ks].h[j] = (unsigned short)(b1 >> 16);
                A2[ks].h[j] = (unsigned short)(b2 >> 16);
                A3[ks].h[j] = (unsigned short)(b3 >> 16);
            }
        }

        f32x4 acc[8];
        #pragma unroll
        for (int nt = 0; nt < 8; ++nt) acc[nt] = (f32x4){0.f, 0.f, 0.f, 0.f};

        #pragma unroll
        for (int nt = 0; nt < 8; ++nt) {
            #pragma unroll
            for (int ks = 0; ks < 2; ++ks) {
                BU B1, B2, B3;
                B1.q = *(const uint4*)(bfr + ((0 * 8 + nt) * 2 + ks) * 256 + lbase);
                B2.q = *(const uint4*)(bfr + ((1 * 8 + nt) * 2 + ks) * 256 + lbase);
                B3.q = *(const uint4*)(bfr + ((2 * 8 + nt) * 2 + ks) * 256 + lbase);
                acc[nt] = __builtin_amdgcn_mfma_f32_16x16x32_bf16(A1[ks].v, B1.v, acc[nt], 0, 0, 0);
                acc[nt] = __builtin_amdgcn_mfma_f32_16x16x32_bf16(A1[ks].v, B2.v, acc[nt], 0, 0, 0);
                acc[nt] = __builtin_amdgcn_mfma_f32_16x16x32_bf16(A2[ks].v, B1.v, acc[nt], 0, 0, 0);
                acc[nt] = __builtin_amdgcn_mfma_f32_16x16x32_bf16(A2[ks].v, B2.v, acc[nt], 0, 0, 0);
                acc[nt] = __builtin_amdgcn_mfma_f32_16x16x32_bf16(A1[ks].v, B3.v, acc[nt], 0, 0, 0);
                acc[nt] = __builtin_amdgcn_mfma_f32_16x16x32_bf16(A3[ks].v, B1.v, acc[nt], 0, 0, 0);
            }
        }

        // per-row top-2 scan over 8 n-tiles (codes ascending) — r9 verbatim
        float s1[4], s2[4]; int c1[4], c2v[4];
        #pragma unroll
        for (int j = 0; j < 4; ++j) { s1[j] = s2[j] = -3.4e38f; c1[j] = c2v[j] = 0; }
        #pragma unroll
        for (int nt = 0; nt < 8; ++nt) {
            const int  code = nt * 16 + (lane & 15);
            const float csub = c2l[code];
            #pragma unroll
            for (int j = 0; j < 4; ++j) {
                float s = acc[nt][j] - csub;
                if (s > s1[j])      { s2[j] = s1[j]; c2v[j] = c1[j]; s1[j] = s; c1[j] = code; }
                else if (s > s2[j]) { s2[j] = s;     c2v[j] = code; }
            }
        }
        // merge across the 16 lanes holding this row (xor 1,2,4,8) — verbatim
        #pragma unroll
        for (int m = 1; m <= 8; m <<= 1) {
            #pragma unroll
            for (int j = 0; j < 4; ++j) {
                float os1 = __shfl_xor(s1[j], m); int oc1 = __shfl_xor(c1[j], m);
                float os2 = __shfl_xor(s2[j], m); int oc2 = __shfl_xor(c2v[j], m);
                bool a  = (os1 > s1[j]) || (os1 == s1[j] && oc1 < c1[j]);
                float n1 = a ? os1 : s1[j]; int nc1 = a ? oc1 : c1[j];
                float l1 = a ? s1[j] : os1; int lc1 = a ? c1[j] : oc1;
                bool bs = (os2 > s2[j]) || (os2 == s2[j] && oc2 < c2v[j]);
                float w2 = bs ? os2 : s2[j]; int wc2 = bs ? oc2 : c2v[j];
                bool c3 = (l1 > w2) || (l1 == w2 && lc1 < wc2);
                s1[j] = n1; c1[j] = nc1;
                s2[j] = c3 ? l1 : w2; c2v[j] = c3 ? lc1 : wc2;
            }
        }
        if ((lane & 15) == 0) {
            const int g = lane >> 4;
            #pragma unroll
            for (int j = 0; j < 4; ++j) {
                int ka = c1[j], kb = c2v[j];
                int kmin = min(ka, kb), kmax = max(ka, kb);
                cand[w * 64 + mt * 16 + g * 4 + j] =
                    ((unsigned int)kmin << 8) | (unsigned int)kmax;
            }
        }
    }
    __syncthreads();

    // EXACT judge, 1 token/thread: round-4 bitwise chains (proven absmax 0)
    {
        unsigned int cp_ = cand[tid];
        int k1 = (int)(cp_ >> 8), k2 = (int)(cp_ & 255u);   // k1 < k2
        const float* zp = z_e + (size_t)b * (size_t)(D_ * T_) + t0 + tid;
        float z[64];
        #pragma unroll
        for (int d = 0; d < 64; ++d) z[d] = zp[(size_t)d * T_];

        float m1, m2;
        {
            const float* cp = centroids + k1 * CODE_DIM;
            float a0 = -c2l[k1], a1 = 0.f;
            #pragma unroll
            for (int d = 0; d < 64; d += 2) {
                a0 = fmaf(cp[d],     z[d],     a0);
                a1 = fmaf(cp[d + 1], z[d + 1], a1);
            }
            m1 = a0 + a1;
        }
        {
            const float* cp = centroids + k2 * CODE_DIM;
            float a0 = -c2l[k2], a1 = 0.f;
            #pragma unroll
            for (int d = 0; d < 64; d += 2) {
                a0 = fmaf(cp[d],     z[d],     a0);
                a1 = fmaf(cp[d + 1], z[d + 1], a1);
            }
            m2 = a0 + a1;
        }
        int bi = (m2 > m1) ? k2 : k1;      // strict: tie keeps lower k
        out_idx[base + tid] = (float)bi;
        atomicAdd(&hist[bi], 1u);
    }
    __syncthreads();
    if (tid < NUM_CODES) {
        unsigned int h = hist[tid];
        if (h) atomicAdd(&counts[tid], h);
    }
}

// ---------------------------------------------------------------------------
// finalize: entropy -> perplexity, usage
// ---------------------------------------------------------------------------
__global__ __launch_bounds__(128) void kmeans_finalize(
    const unsigned int* __restrict__ counts, float* __restrict__ out)
{
    const int k = threadIdx.x;
    unsigned int c = counts[k];
    float p = fmaxf((float)c * (1.0f / (float)N_TOK), 1e-12f);
    float h = -p * logf(p);
    float u = (c > 0u) ? 1.0f : 0.0f;

    __shared__ float sh[NUM_CODES];
    __shared__ float su[NUM_CODES];
    sh[k] = h; su[k] = u;
    __syncthreads();
    for (int s = 64; s > 0; s >>= 1) {
        if (k < s) { sh[k] += sh[k + s]; su[k] += su[k + s]; }
        __syncthreads();
    }
    if (k == 0) {
        out[N_TOK + 0] = expf(sh[0]);
        out[N_TOK + 1] = su[0] * (1.0f / 128.f);
    }
}

// ---------------------------------------------------------------------------
extern "C" void kernel_launch(void* const* d_in, const int* in_sizes, int n_in,
                              void* d_out, int out_size, void* d_ws, size_t ws_size,
                              hipStream_t stream)
{
    const float* z_e       = (const float*)d_in[0];
    const float* centroids = (const float*)d_in[1];
    float* out  = (float*)d_out;
    float* ws_f = (float*)d_ws;
    unsigned int* counts = (unsigned int*)(ws_f + 128);

    kmeans_prep<<<1, 256, 0, stream>>>(centroids, ws_f);
    kmeans_assign<<<N_TOK / 256, 256, 0, stream>>>(z_e, centroids, ws_f, counts, out);
    kmeans_finalize<<<1, 128, 0, stream>>>(counts, out);
}